// Round 6
// baseline (40.848 us; speedup 1.0000x reference)
//
#include <hip/hip_runtime.h>
#include <math.h>

// Problem constants
#define BB 512      // batch (edges)
#define NN 4096     // nodes
#define LL 128      // feature dim
#define IN_DIM 385  // 3*L + ND
#define IN_PAD 388  // padded to multiple of 4
#define NK4_1 97    // ceil(IN_DIM/4) k-groups for layer 1
#define EPB 2       // edges per block (edge kernel)
#define TASKS 1024  // 2 * BB  (src/tar messages)
#define GPB 4       // tasks per block (gru kernel)

// ---------------------------------------------------------------------------
// Workspace layout (float offsets). NOTHING here needs pre-initialization:
// msgs/nodes are written densely by the edge kernel; w1p fully by prep.
// ---------------------------------------------------------------------------
#define OFF_MSGS  0                          // msgs[task][LL]      (1024*128)
#define OFF_NODES (OFF_MSGS + TASKS * LL)    // node id per task    (1024 ints)
#define OFF_W1PS  (OFF_NODES + TASKS)        // src w1 packed f4[k4*LL + j]
#define OFF_W1PT  (OFF_W1PS + NK4_1 * LL * 4)
// end = 132096 + 2*49664 = 231424 floats ~ 0.93 MB

// ---------------------------------------------------------------------------
// Prep: ONLY pack layer-1 weights (row stride 385 is odd -> unaligned for
// float4; everything else in this problem is already 16B-aligned row-major
// and is read directly). ~0.8 MB of traffic.
// w1p[k4*128 + j] = float4(w1[j][4k4 .. 4k4+3]), zero-padded past 385.
// ---------------------------------------------------------------------------
__global__ __launch_bounds__(256) void prep_kernel(
    const float* __restrict__ sw1, const float* __restrict__ tw1,
    float* __restrict__ ws)
{
    const int i = blockIdx.x * 256 + threadIdx.x;
    const int stride = gridDim.x * 256;

    float4* w1ps = (float4*)(ws + OFF_W1PS);
    float4* w1pt = (float4*)(ws + OFF_W1PT);
    for (int idx = i; idx < NK4_1 * LL; idx += stride) {
        const int k4 = idx >> 7, j = idx & 127;
        const int k = k4 * 4;
        float4 a, b;
        a.x = sw1[j * IN_DIM + k];     b.x = tw1[j * IN_DIM + k];
        a.y = (k + 1 < IN_DIM) ? sw1[j * IN_DIM + k + 1] : 0.f;
        b.y = (k + 1 < IN_DIM) ? tw1[j * IN_DIM + k + 1] : 0.f;
        a.z = (k + 2 < IN_DIM) ? sw1[j * IN_DIM + k + 2] : 0.f;
        b.z = (k + 2 < IN_DIM) ? tw1[j * IN_DIM + k + 2] : 0.f;
        a.w = (k + 3 < IN_DIM) ? sw1[j * IN_DIM + k + 3] : 0.f;
        b.w = (k + 3 < IN_DIM) ? tw1[j * IN_DIM + k + 3] : 0.f;
        w1ps[idx] = a; w1pt[idx] = b;
    }
}

// ---------------------------------------------------------------------------
// Edge messages. Blocks 0..511: one side of EPB=2 edges (r5-proven math).
// Layer 2 reads ORIGINAL w2 directly (rows are 512B-aligned, float4-able).
// Output: dense msgs[task][j] + nodes[task] -- no atomics, no shared accum.
// Blocks 512..543: passthrough copy memory -> out (GRU overwrites seen rows).
// ---------------------------------------------------------------------------
__global__ __launch_bounds__(256) void edge_msg_kernel(
    const float* __restrict__ x,        // (B, N, 1)
    const float* __restrict__ memory,   // (N, L)
    const float* __restrict__ delta_t,  // (B, N, L)
    const float* __restrict__ sb1, const float* __restrict__ sw2,
    const float* __restrict__ sb2,
    const float* __restrict__ tb1, const float* __restrict__ tw2,
    const float* __restrict__ tb2,
    const int* __restrict__ source, const int* __restrict__ target,
    float* __restrict__ ws, float* __restrict__ out)
{
    const int tid = threadIdx.x;

    // ---- copy blocks ----
    if (blockIdx.x >= 512) {
        const int cb = blockIdx.x - 512;
        float4* out4 = (float4*)out;
        const float4* mem4 = (const float4*)memory;
        for (int idx = cb * 256 + tid; idx < NN * LL / 4; idx += 32 * 256)
            out4[idx] = mem4[idx];
        return;
    }

    // ---- edge blocks ----
    const int side  = blockIdx.x & 1;
    const int chunk = blockIdx.x >> 1;       // 0 .. 255
    const int g     = tid >> 7;              // k-split group
    const int j     = tid & 127;             // output feature

    __shared__ float in2[IN_PAD][EPB];
    __shared__ float h1[LL][EPB];
    __shared__ float part1[2][EPB][LL];
    __shared__ float part2[2][EPB][LL];
    __shared__ int   node_sh[EPB];

    const float4* w1p = (const float4*)(ws + (side ? OFF_W1PT : OFF_W1PS));
    const float* w2  = side ? tw2 : sw2;
    const float* b1  = side ? tb1 : sb1;
    const float* b2  = side ? tb2 : sb2;

    // Stage EPB edges' input vectors (pad -> 0).
    #pragma unroll
    for (int e = 0; e < EPB; ++e) {
        const int eg = chunk * EPB + e;
        const int s = source[eg], t = target[eg];
        const int node  = side ? t : s;
        const int other = side ? s : t;
        if (tid == 0) node_sh[e] = node;
        for (int idx = tid; idx < IN_PAD; idx += 256) {
            float v = 0.0f;
            if (idx < LL)           v = memory[node * LL + idx];
            else if (idx < 2 * LL)  v = memory[other * LL + (idx - LL)];
            else if (idx < 3 * LL)  v = delta_t[((size_t)eg * NN + node) * LL + (idx - 2 * LL)];
            else if (idx == 3 * LL) v = x[(size_t)eg * NN + node];
            in2[idx][e] = v;
        }
    }
    __syncthreads();

    // Layer 1 (packed w1): g0 -> k4 [0,49), g1 -> [49,97)
    {
        const int k40 = g ? 49 : 0;
        const int k41 = g ? NK4_1 : 49;
        float a0 = 0.f, a1 = 0.f;
        #pragma unroll 4
        for (int k4 = k40; k4 < k41; ++k4) {
            const float4 w  = w1p[k4 * LL + j];
            const float4 i0 = *(const float4*)&in2[k4 * 4][0];
            const float4 i1 = *(const float4*)&in2[k4 * 4 + 2][0];
            a0 = fmaf(w.x, i0.x, a0); a1 = fmaf(w.x, i0.y, a1);
            a0 = fmaf(w.y, i0.z, a0); a1 = fmaf(w.y, i0.w, a1);
            a0 = fmaf(w.z, i1.x, a0); a1 = fmaf(w.z, i1.y, a1);
            a0 = fmaf(w.w, i1.z, a0); a1 = fmaf(w.w, i1.w, a1);
        }
        part1[g][0][j] = a0;
        part1[g][1][j] = a1;
    }
    __syncthreads();

    h1[j][g] = fmaxf(part1[0][g][j] + part1[1][g][j] + b1[j], 0.0f);
    __syncthreads();

    // Layer 2 (DIRECT original w2, rows 16B-aligned): g0 k [0,64), g1 [64,128)
    {
        const int k0 = g * 64;
        float a0 = 0.f, a1 = 0.f;
        #pragma unroll 4
        for (int i = 0; i < 16; ++i) {
            const int k = k0 + 4 * i;
            const float4 w  = *(const float4*)&w2[j * LL + k];
            const float4 hA = *(const float4*)&h1[k][0];
            const float4 hB = *(const float4*)&h1[k + 2][0];
            a0 = fmaf(w.x, hA.x, a0); a1 = fmaf(w.x, hA.y, a1);
            a0 = fmaf(w.y, hA.z, a0); a1 = fmaf(w.y, hA.w, a1);
            a0 = fmaf(w.z, hB.x, a0); a1 = fmaf(w.z, hB.y, a1);
            a0 = fmaf(w.w, hB.z, a0); a1 = fmaf(w.w, hB.w, a1);
        }
        part2[g][0][j] = a0;
        part2[g][1][j] = a1;
    }
    __syncthreads();

    // Dense message write; thread (g,j) finishes edge e=g.
    {
        const float m = part2[0][g][j] + part2[1][g][j] + b2[j];
        const int task = side * BB + chunk * EPB + g;
        ws[OFF_MSGS + task * LL + j] = m;
        if (j == 0)
            ((int*)ws)[OFF_NODES + task] = node_sh[g];
    }
}

// ---------------------------------------------------------------------------
// GRU: 256 blocks x GPB=4 task-slots. Each block scans the 1024-entry node
// array (in LDS) to find, per slot: all tasks sharing its node (sorted ->
// deterministic sum), and ownership (min task == this task). Owned slots run
// the GRU (gate-split, direct 16B-aligned wih/whh reads) and write out.
// ---------------------------------------------------------------------------
__global__ __launch_bounds__(256) void gru_kernel(
    const float* __restrict__ memory,
    const float* __restrict__ wih, const float* __restrict__ whh,
    const float* __restrict__ bih, const float* __restrict__ bhh,
    float* __restrict__ ws, float* __restrict__ out)
{
    const int tid = threadIdx.x;
    const int g = tid >> 7, j = tid & 127;

    __shared__ int   snodes[TASKS];          // 4 KB
    __shared__ int   matches[GPB][TASKS];    // 16 KB (worst case)
    __shared__ int   cnt_sh[GPB];
    __shared__ int   nd_sh[GPB];
    __shared__ float ah[LL][2 * GPB];        // [k][slot] 0..3=agg, 4..7=h
    __shared__ float gates[6][GPB][LL];

    const int* nodes_arr = (const int*)ws + OFF_NODES;

    for (int e = tid; e < TASKS; e += 256)
        snodes[e] = nodes_arr[e];
    if (tid < GPB) cnt_sh[tid] = 0;
    __syncthreads();

    if (tid < GPB)
        nd_sh[tid] = snodes[blockIdx.x * GPB + tid];
    __syncthreads();

    // Scan all tasks for matches against this block's 4 slot-nodes.
    for (int e = tid; e < TASKS; e += 256) {
        const int ne = snodes[e];
        #pragma unroll
        for (int s = 0; s < GPB; ++s) {
            if (ne == nd_sh[s]) {
                const int p = atomicAdd(&cnt_sh[s], 1);
                matches[s][p] = e;
            }
        }
    }
    __syncthreads();

    // Sort each slot's match list (tiny; deterministic sum order + owner=min).
    if (tid < GPB) {
        const int c = cnt_sh[tid];
        int* m = matches[tid];
        for (int a = 1; a < c; ++a) {
            const int v = m[a];
            int b = a - 1;
            while (b >= 0 && m[b] > v) { m[b + 1] = m[b]; --b; }
            m[b + 1] = v;
        }
    }
    __syncthreads();

    // Stage agg (g=0) and h (g=1) for the 4 slots, coalesced over j.
    #pragma unroll
    for (int s = 0; s < GPB; ++s) {
        if (g == 0) {
            const int c = cnt_sh[s];
            float a = 0.0f;
            for (int m = 0; m < c; ++m)
                a += ws[OFF_MSGS + matches[s][m] * LL + j];
            ah[j][s] = a / (float)c;         // c >= 1 (self-match)
        } else {
            ah[j][GPB + s] = memory[nd_sh[s] * LL + j];
        }
    }
    __syncthreads();

    // Gate-split matvec: g0 -> wih vs agg, g1 -> whh vs h. Direct reads:
    // row (gate*128 + j) of (384,128) is 512B-aligned -> float4.
    const float* wmat = g ? whh : wih;
    float a0[GPB] = {}, a1[GPB] = {}, a2[GPB] = {};
    #pragma unroll 2
    for (int k4 = 0; k4 < 32; ++k4) {
        const float4 w0 = *(const float4*)&wmat[(0 * LL + j) * LL + 4 * k4];
        const float4 w1 = *(const float4*)&wmat[(1 * LL + j) * LL + 4 * k4];
        const float4 w2 = *(const float4*)&wmat[(2 * LL + j) * LL + 4 * k4];
        const float w0a[4] = {w0.x, w0.y, w0.z, w0.w};
        const float w1a[4] = {w1.x, w1.y, w1.z, w1.w};
        const float w2a[4] = {w2.x, w2.y, w2.z, w2.w};
        #pragma unroll
        for (int c = 0; c < 4; ++c) {
            const float4 v4 = *(const float4*)&ah[k4 * 4 + c][g * GPB];
            const float va[4] = {v4.x, v4.y, v4.z, v4.w};
            #pragma unroll
            for (int s = 0; s < GPB; ++s) {
                a0[s] = fmaf(w0a[c], va[s], a0[s]);
                a1[s] = fmaf(w1a[c], va[s], a1[s]);
                a2[s] = fmaf(w2a[c], va[s], a2[s]);
            }
        }
    }
    #pragma unroll
    for (int s = 0; s < GPB; ++s) {
        gates[g * 3 + 0][s][j] = a0[s];
        gates[g * 3 + 1][s][j] = a1[s];
        gates[g * 3 + 2][s][j] = a2[s];
    }
    __syncthreads();

    // Finalize owned slots only (owner = min matching task == slot's task).
    for (int o = tid; o < GPB * LL; o += 256) {
        const int s = o >> 7, jj = o & 127;
        const int task = blockIdx.x * GPB + s;
        if (matches[s][0] != task) continue;   // not owner (duplicate node)
        const float ir = gates[0][s][jj] + bih[jj];
        const float iz = gates[1][s][jj] + bih[LL + jj];
        const float inn = gates[2][s][jj] + bih[2 * LL + jj];
        const float hr = gates[3][s][jj] + bhh[jj];
        const float hz = gates[4][s][jj] + bhh[LL + jj];
        const float hn = gates[5][s][jj] + bhh[2 * LL + jj];
        const float r = 1.0f / (1.0f + __expf(-(ir + hr)));
        const float z = 1.0f / (1.0f + __expf(-(iz + hz)));
        const float n = tanhf(inn + r * hn);
        const float h = ah[jj][GPB + s];
        out[nd_sh[s] * LL + jj] = (1.0f - z) * n + z * h;
    }
}

// ---------------------------------------------------------------------------
extern "C" void kernel_launch(void* const* d_in, const int* in_sizes, int n_in,
                              void* d_out, int out_size, void* d_ws, size_t ws_size,
                              hipStream_t stream) {
    const float* x        = (const float*)d_in[0];
    const float* memory   = (const float*)d_in[1];
    const float* delta_t  = (const float*)d_in[2];
    const float* src_w1   = (const float*)d_in[3];
    const float* src_b1   = (const float*)d_in[4];
    const float* src_w2   = (const float*)d_in[5];
    const float* src_b2   = (const float*)d_in[6];
    const float* tar_w1   = (const float*)d_in[7];
    const float* tar_b1   = (const float*)d_in[8];
    const float* tar_w2   = (const float*)d_in[9];
    const float* tar_b2   = (const float*)d_in[10];
    const float* gru_wih  = (const float*)d_in[11];
    const float* gru_whh  = (const float*)d_in[12];
    const float* gru_bih  = (const float*)d_in[13];
    const float* gru_bhh  = (const float*)d_in[14];
    const int*   source   = (const int*)d_in[15];
    const int*   target   = (const int*)d_in[16];

    float* out = (float*)d_out;
    float* ws  = (float*)d_ws;

    // 1) pack w1 (src+tar) only -- everything else reads original layout
    prep_kernel<<<256, 256, 0, stream>>>(src_w1, tar_w1, ws);

    // 2) edge messages (512 blocks) + memory->out copy (32 blocks)
    edge_msg_kernel<<<544, 256, 0, stream>>>(
        x, memory, delta_t,
        src_b1, src_w2, src_b2, tar_b1, tar_w2, tar_b2,
        source, target, ws, out);

    // 3) GRU over all 1024 task-slots (scan-based segment aggregation)
    gru_kernel<<<TASKS / GPB, 256, 0, stream>>>(
        memory, gru_wih, gru_whh, gru_bih, gru_bhh, ws, out);
}